// Round 4
// baseline (225.437 us; speedup 1.0000x reference)
//
#include <hip/hip_runtime.h>

// LongTermSpectralFlatness: x (32, 3000, 201, 2) fp32 -> flatness (32, 3000, 1) fp32
//
// Math (t >= 1):
//   s[t,f]     = (re^2+im^2) * scale[f] * hamm_sq_sum(25)/16000/10
//   welch[t,f] = mean(s[t-10..t-1, f])                  (cnt = max(min(t,10),1))
//   am[t,f]    = mean(welch[t-30..t-1, f]) + 1e-5
//   gm[t,f]    = exp(mean(log(welch[t-30..t-1,f]+1e-5)))   (the -eps+eps cancels!)
//   flat[t]    = log10(2) * sum_f ( log2(am) - mean(log2(welch+eps)) ),  flat[0] = 0
//
// R11: R8/R9/R10 all neutral => code layout, unroll, group size are not the
// limiter. Model: total input 154 MB < 256 MB LLC => halo re-reads are
// LLC-absorbed, HBM floor ~24.5 us; kernel sits at ~40 us with per-frame wall
// ~170-210 cyc vs ~75 cyc issue => STALL-bound (serial log/shuffle/load
// chains) at only ~2 waves/SIMD (480 blocks = 7.5 waves/CU). Total waves are
// fixed by the problem, so more waves/SIMD needs more blocks: LTILE 200->100
// (grid 960) + __launch_bounds__(256,4) => 4 blocks/CU = 4 waves/SIMD, 2x
// stall hiding. Extra halo bytes (+31 MB logical) are LLC-absorbed — the R8
// big-tile rationale inverts. Revert to 5-frame groups (buffer VGPRs 30, live
// ~95 <= 128 cap at 4 waves/EU; 10-frame groups would exceed). Both tile
// paths straight-line. Fold: rr = fma(la, L, -lsum*(inv30*L)).
// Keep: no l_ring (evict log recomputed from w_ring bitwise-identically),
// 4-step swizzle-only butterfly {16,8,4,2}, pointer-bump addressing,
// batch-fastest grid (halo source tile same XCD), triple-buffer distance-2
// prefetch.

constexpr int TT = 3000;
constexpr int FF = 201;
constexpr int BB = 32;
constexpr int W1 = 10;
constexpr int W2 = 30;
constexpr int HALO = 40;    // W1 + W2
constexpr int LTILE = 100;  // output frames per tile
constexpr int NT = 30;      // 30 * 100 = 3000
#define EPSV 1e-5f
#define CSCALE (9.935f / 160000.0f)  // hamming_sq_sum(25)/16000/M
#define LOG10_2 0.3010299956639812f

#define BUFSEL(I) ((I) % 3 == 0 ? bufA : ((I) % 3 == 1 ? bufB : bufC))

/* Prefetch group GI+2 (5 frames) into its rotation slot. Terminal groups
   re-read the last valid base: wasted but in-bounds (L1 hit). */
#define PF_GROUP(GI, GTOT)                                                     \
  {                                                                            \
    const float2* pn = ((GI) + 2 < (GTOT)) ? (pf2 + 5 * FF) : pf2;             \
    float2* nb = BUFSEL((GI) + 2);                                             \
    _Pragma("unroll") for (int j = 0; j < 5; ++j) nb[j] = pn[j * FF];          \
    pf2 = pn;                                                                  \
  }

/* Warm-up A (non-first, GI=0..1): squares of stream frames -> s_ring. */
#define WARMA_GROUP(GI)                                                        \
  {                                                                            \
    PF_GROUP(GI, 28);                                                          \
    float2* cb = BUFSEL(GI);                                                   \
    _Pragma("unroll") for (int j = 0; j < 5; ++j) {                            \
      float sv = fmaf(cb[j].x, cb[j].x, cb[j].y * cb[j].y) * cs;               \
      ssum += sv;                                                              \
      s_ring[(GI) * 5 + j] = sv;                                               \
    }                                                                          \
  }

/* Warm-up B (non-first, GI=2..7): welch/log fill for warm frames
   wf = (GI-2)*5 + j (t = t0-30+wf >= 70), full 10-window always. */
#define WARMB_GROUP(GI)                                                        \
  {                                                                            \
    PF_GROUP(GI, 28);                                                          \
    float2* cb = BUFSEL(GI);                                                   \
    _Pragma("unroll") for (int j = 0; j < 5; ++j) {                            \
      const int wf = ((GI) - 2) * 5 + j;                                       \
      float welch = ssum * 0.1f;                                               \
      float lw = __log2f(welch + EPSV);                                        \
      wsum += welch; w_ring[wf] = welch;                                       \
      lsum += lw;                                                              \
      float sv = fmaf(cb[j].x, cb[j].x, cb[j].y * cb[j].y) * cs;               \
      ssum += sv - s_ring[wf % 10];                                            \
      s_ring[wf % 10] = sv;                                                    \
    }                                                                          \
  }

/* Main: 5 output frames. MB = compile-time main-frame base (multiple of 5).
   m = MB+j; fr = m%30 = (MB%30)+j (no wrap); s_ring slot = m%10 (no wrap).
   DYN (tile 0, m<30): dynamic counts (constant-folded) + no lsum eviction.
   Non-DYN eviction recomputes the evicted log from w_ring: bitwise equal
   to the lw pushed 30 frames earlier. */
#define MAIN_GROUP(GI, GTOT, MB, DYN)                                          \
  {                                                                            \
    PF_GROUP(GI, GTOT);                                                        \
    float2* cb = BUFSEL(GI);                                                   \
    float rr[5];                                                               \
    _Pragma("unroll") for (int j = 0; j < 5; ++j) {                            \
      const int m = (MB) + j;                                                  \
      const int fr = m % 30;                                                   \
      float inv10, inv30;                                                      \
      if (DYN) {                                                               \
        inv10 = 1.0f / (float)max(min(m, W1), 1);                              \
        inv30 = 1.0f / (float)max(min(m, W2), 1);                              \
      } else {                                                                 \
        inv10 = 0.1f;                                                          \
        inv30 = (1.0f / 30.0f);                                                \
      }                                                                        \
      float welch = ssum * inv10;                                              \
      float lw = __log2f(welch + EPSV);                                        \
      float am = fmaf(wsum, inv30, EPSV);                                      \
      float la = __log2f(am);                                                  \
      rr[j] = fmaf(la, LOG10_2, -(lsum * (inv30 * LOG10_2)));                  \
      float wold = w_ring[fr];                                                 \
      if (DYN) lsum += lw;                                                     \
      else     lsum += lw - __log2f(wold + EPSV);                              \
      wsum += welch - wold;                                                    \
      w_ring[fr] = welch;                                                      \
      float sv = fmaf(cb[j].x, cb[j].x, cb[j].y * cb[j].y) * cs;               \
      ssum += sv - s_ring[m % 10];                                             \
      s_ring[m % 10] = sv;                                                     \
    }                                                                          \
    /* 4-step butterfly, swizzle-only masks; partials in lanes 0,1,32,33 */    \
    _Pragma("unroll") for (int off = 16; off >= 2; off >>= 1) {                \
      _Pragma("unroll") for (int j = 0; j < 5; ++j)                            \
          rr[j] += __shfl_xor(rr[j], off, 64);                                 \
    }                                                                          \
    if ((lane & 30) == 0) {                                                    \
      const int p = (lane & 1) | ((lane >> 4) & 2);                            \
      _Pragma("unroll") for (int j = 0; j < 5; ++j)                            \
          ((float*)&part[wv][(MB) + j])[p] = rr[j];                            \
    }                                                                          \
  }

__global__ __launch_bounds__(256, 4)
void ltsf_kernel(const float2* __restrict__ x, float* __restrict__ out) {
  const int tid = threadIdx.x;
  const int b = blockIdx.x;     // batch fastest: tile & tile-1 same XCD (%8)
  const int tile = blockIdx.y;
  const int t0 = tile * LTILE;
  const bool first = (tile == 0);
  const int tstart = first ? 0 : (t0 - HALO);
  const int lane = tid & 63;
  const int wv = tid >> 6;

  // freq bin; lanes >= 201 are zero-scale (their contrib is exactly 0 for t>=1)
  const int f = (tid < FF) ? tid : (FF - 1);
  float cs = (tid < FF) ? ((tid == 0 || tid == FF - 1) ? 1.0f : 2.0f) : 0.0f;
  cs *= CSCALE;

  const float2* xb = x + (size_t)b * TT * FF;

  __shared__ float4 part[4][LTILE];

  float s_ring[W1], w_ring[W2];
#pragma unroll
  for (int j = 0; j < W1; ++j) s_ring[j] = 0.f;
#pragma unroll
  for (int j = 0; j < W2; ++j) w_ring[j] = 0.f;
  float ssum = 0.f, wsum = 0.f, lsum = 0.f;

  float2 bufA[5], bufB[5], bufC[5];

  // preload stream groups 0 and 1; pf2 tracks the last-loaded group base
  const float2* p0 = xb + (size_t)tstart * FF + f;
#pragma unroll
  for (int j = 0; j < 5; ++j) bufA[j] = p0[j * FF];
  const float2* pf2 = p0 + 5 * FF;
#pragma unroll
  for (int j = 0; j < 5; ++j) bufB[j] = pf2[j * FF];

  if (!first) {
    // stream: 2 warm-A + 6 warm-B + 20 main = 28 straight-line groups
    // (frames t0-40..t0+99)
    WARMA_GROUP(0)  WARMA_GROUP(1)
    WARMB_GROUP(2)  WARMB_GROUP(3)  WARMB_GROUP(4)
    WARMB_GROUP(5)  WARMB_GROUP(6)  WARMB_GROUP(7)
    MAIN_GROUP(8,  28,  0, false)  MAIN_GROUP(9,  28,  5, false)
    MAIN_GROUP(10, 28, 10, false)  MAIN_GROUP(11, 28, 15, false)
    MAIN_GROUP(12, 28, 20, false)  MAIN_GROUP(13, 28, 25, false)
    MAIN_GROUP(14, 28, 30, false)  MAIN_GROUP(15, 28, 35, false)
    MAIN_GROUP(16, 28, 40, false)  MAIN_GROUP(17, 28, 45, false)
    MAIN_GROUP(18, 28, 50, false)  MAIN_GROUP(19, 28, 55, false)
    MAIN_GROUP(20, 28, 60, false)  MAIN_GROUP(21, 28, 65, false)
    MAIN_GROUP(22, 28, 70, false)  MAIN_GROUP(23, 28, 75, false)
    MAIN_GROUP(24, 28, 80, false)  MAIN_GROUP(25, 28, 85, false)
    MAIN_GROUP(26, 28, 90, false)  MAIN_GROUP(27, 28, 95, false)
  } else {
    // tile 0: 20 straight-line main groups (frames 0..99); m<30 DYN
    // (constant-folded), no eviction there.
    MAIN_GROUP(0,  20,  0, true)   MAIN_GROUP(1,  20,  5, true)
    MAIN_GROUP(2,  20, 10, true)   MAIN_GROUP(3,  20, 15, true)
    MAIN_GROUP(4,  20, 20, true)   MAIN_GROUP(5,  20, 25, true)
    MAIN_GROUP(6,  20, 30, false)  MAIN_GROUP(7,  20, 35, false)
    MAIN_GROUP(8,  20, 40, false)  MAIN_GROUP(9,  20, 45, false)
    MAIN_GROUP(10, 20, 50, false)  MAIN_GROUP(11, 20, 55, false)
    MAIN_GROUP(12, 20, 60, false)  MAIN_GROUP(13, 20, 65, false)
    MAIN_GROUP(14, 20, 70, false)  MAIN_GROUP(15, 20, 75, false)
    MAIN_GROUP(16, 20, 80, false)  MAIN_GROUP(17, 20, 85, false)
    MAIN_GROUP(18, 20, 90, false)  MAIN_GROUP(19, 20, 95, false)
  }

  // ---- epilogue: sum the 16 partials (4 waves x 4 lanes) per frame ----
  __syncthreads();
  if (tid < LTILE) {
    float4 v0 = part[0][tid], v1 = part[1][tid];
    float4 v2 = part[2][tid], v3 = part[3][tid];
    float v = ((v0.x + v0.y) + (v0.z + v0.w)) + ((v1.x + v1.y) + (v1.z + v1.w)) +
              ((v2.x + v2.y) + (v2.z + v2.w)) + ((v3.x + v3.y) + (v3.z + v3.w));
    if (first && tid == 0) v = 0.f;  // reference forces frame 0 to exactly 0
    out[(size_t)b * TT + t0 + tid] = v;
  }
}

extern "C" void kernel_launch(void* const* d_in, const int* in_sizes, int n_in,
                              void* d_out, int out_size, void* d_ws, size_t ws_size,
                              hipStream_t stream) {
  const float2* x = (const float2*)d_in[0];
  float* out = (float*)d_out;
  dim3 grid(BB, NT);  // batch fastest: halo source tile lands on same XCD
  ltsf_kernel<<<grid, 256, 0, stream>>>(x, out);
}

// Round 5
// 219.950 us; speedup vs baseline: 1.0249x; 1.0249x over previous
//
#include <hip/hip_runtime.h>

// LongTermSpectralFlatness: x (32, 3000, 201, 2) fp32 -> flatness (32, 3000, 1) fp32
//
// Math (t >= 1):
//   s[t,f]     = (re^2+im^2) * scale[f] * hamm_sq_sum(25)/16000/10
//   welch[t,f] = mean(s[t-10..t-1, f])                  (cnt = max(min(t,10),1))
//   am[t,f]    = mean(welch[t-30..t-1, f]) + 1e-5
//   gm[t,f]    = exp(mean(log(welch[t-30..t-1,f]+1e-5)))   (the -eps+eps cancels!)
//   flat[t]    = log10(2) * sum_f ( log2(am) - mean(log2(welch+eps)) ),  flat[0] = 0
//
// R12: R11 regressed — (256,4) halved VGPRs to 64 (< ~95 live) -> spills
// (cold dispatch 173 us, occ 3.3%). Reverted to (256,2). R8-R11 showed bytes,
// layout, group size, occupancy are ALL neutral: the kernel is pinned ~40 us
// vs 24.5 us HBM floor. Surviving theory: the "distance-2 prefetch" exists
// only in source order — the scheduler sinks buffer loads toward their use
// (shrinks live ranges; live ~95 is too lean for 2 groups in flight), so
// every group pays full loaded-HBM latency. Fix: one
// __builtin_amdgcn_sched_barrier(0) after each group's prefetch loads. Loads
// cannot sink past it; waitcnt pass then emits counted vmcnt(N) two groups
// downstream -> the distance-2 pipeline becomes real. One pin per group
// (not m141-style full pinning).
// Keep: LTILE=200 (amplification 1.2x), 10-frame groups, straight-line both
// tiles, no l_ring (evict log recomputed from w_ring bitwise-identically),
// 4-step swizzle-only butterfly {16,8,4,2}, pointer-bump addressing,
// batch-fastest grid, triple-buffer rotation, __launch_bounds__(256,2).

constexpr int TT = 3000;
constexpr int FF = 201;
constexpr int BB = 32;
constexpr int W1 = 10;
constexpr int W2 = 30;
constexpr int HALO = 40;    // W1 + W2
constexpr int LTILE = 200;  // output frames per tile
constexpr int NT = 15;      // 15 * 200 = 3000
#define EPSV 1e-5f
#define CSCALE (9.935f / 160000.0f)  // hamming_sq_sum(25)/16000/M
#define LOG10_2 0.3010299956639812f

#define BUFSEL(I) ((I) % 3 == 0 ? bufA : ((I) % 3 == 1 ? bufB : bufC))

/* Prefetch group GI+2 (10 frames) into its rotation slot, then PIN the loads
   with sched_barrier(0) so the scheduler cannot sink them into/past the
   group's compute. Terminal groups re-read the last valid base: wasted but
   in-bounds (L1 hit). */
#define PF_GROUP(GI, GTOT)                                                     \
  {                                                                            \
    const float2* pn = ((GI) + 2 < (GTOT)) ? (pf2 + 10 * FF) : pf2;            \
    float2* nb = BUFSEL((GI) + 2);                                             \
    _Pragma("unroll") for (int j = 0; j < 10; ++j) nb[j] = pn[j * FF];         \
    __builtin_amdgcn_sched_barrier(0);                                         \
    pf2 = pn;                                                                  \
  }

/* Warm-up A (non-first, GI=0): squares of stream frames 0..9 -> s_ring. */
#define WARMA_GROUP(GI, GTOT)                                                  \
  {                                                                            \
    PF_GROUP(GI, GTOT);                                                        \
    float2* cb = BUFSEL(GI);                                                   \
    _Pragma("unroll") for (int j = 0; j < 10; ++j) {                           \
      float sv = fmaf(cb[j].x, cb[j].x, cb[j].y * cb[j].y) * cs;               \
      ssum += sv;                                                              \
      s_ring[j] = sv;                                                          \
    }                                                                          \
  }

/* Warm-up B (non-first, GI=1..3): welch/log fill for warm frames
   wf = (GI-1)*10 + j (t = t0-30+wf), full 10-window always (t >= 170). */
#define WARMB_GROUP(GI, GTOT)                                                  \
  {                                                                            \
    PF_GROUP(GI, GTOT);                                                        \
    float2* cb = BUFSEL(GI);                                                   \
    _Pragma("unroll") for (int j = 0; j < 10; ++j) {                           \
      const int wf = ((GI) - 1) * 10 + j;                                      \
      float welch = ssum * 0.1f;                                               \
      float lw = __log2f(welch + EPSV);                                        \
      wsum += welch; w_ring[wf] = welch;                                       \
      lsum += lw;                                                              \
      float sv = fmaf(cb[j].x, cb[j].x, cb[j].y * cb[j].y) * cs;               \
      ssum += sv - s_ring[j];                                                  \
      s_ring[j] = sv;                                                          \
    }                                                                          \
  }

/* Main: 10 output frames, MB = compile-time main-frame base (multiple of 10).
   m = MB+j; fr = m%30 = (MB%30)+j (no wrap); s_ring slot = m%10 = j.
   DYN (tile 0, m<30): dynamic counts (constant-folded) + no lsum eviction.
   Non-DYN eviction recomputes the evicted log from w_ring: bitwise equal
   to the lw pushed 30 frames earlier. */
#define MAIN_GROUP(GI, GTOT, MB, DYN)                                          \
  {                                                                            \
    PF_GROUP(GI, GTOT);                                                        \
    float2* cb = BUFSEL(GI);                                                   \
    float rr[10];                                                              \
    _Pragma("unroll") for (int j = 0; j < 10; ++j) {                           \
      const int m = (MB) + j;                                                  \
      const int fr = m % 30;                                                   \
      float inv10, inv30;                                                      \
      if (DYN) {                                                               \
        inv10 = 1.0f / (float)max(min(m, W1), 1);                              \
        inv30 = 1.0f / (float)max(min(m, W2), 1);                              \
      } else {                                                                 \
        inv10 = 0.1f;                                                          \
        inv30 = (1.0f / 30.0f);                                                \
      }                                                                        \
      float welch = ssum * inv10;                                              \
      float lw = __log2f(welch + EPSV);                                        \
      float am = fmaf(wsum, inv30, EPSV);                                      \
      float la = __log2f(am);                                                  \
      rr[j] = fmaf(la, LOG10_2, -(lsum * (inv30 * LOG10_2)));                  \
      float wold = w_ring[fr];                                                 \
      if (DYN) lsum += lw;                                                     \
      else     lsum += lw - __log2f(wold + EPSV);                              \
      wsum += welch - wold;                                                    \
      w_ring[fr] = welch;                                                      \
      float sv = fmaf(cb[j].x, cb[j].x, cb[j].y * cb[j].y) * cs;               \
      ssum += sv - s_ring[j];                                                  \
      s_ring[j] = sv;                                                          \
    }                                                                          \
    /* 4-step butterfly, swizzle-only masks; partials in lanes 0,1,32,33 */    \
    _Pragma("unroll") for (int off = 16; off >= 2; off >>= 1) {                \
      _Pragma("unroll") for (int j = 0; j < 10; ++j)                           \
          rr[j] += __shfl_xor(rr[j], off, 64);                                 \
    }                                                                          \
    if ((lane & 30) == 0) {                                                    \
      const int p = (lane & 1) | ((lane >> 4) & 2);                            \
      _Pragma("unroll") for (int j = 0; j < 10; ++j)                           \
          ((float*)&part[wv][(MB) + j])[p] = rr[j];                            \
    }                                                                          \
  }

__global__ __launch_bounds__(256, 2)
void ltsf_kernel(const float2* __restrict__ x, float* __restrict__ out) {
  const int tid = threadIdx.x;
  const int b = blockIdx.x;     // batch fastest: tile & tile-1 same XCD (%8)
  const int tile = blockIdx.y;
  const int t0 = tile * LTILE;
  const bool first = (tile == 0);
  const int tstart = first ? 0 : (t0 - HALO);
  const int lane = tid & 63;
  const int wv = tid >> 6;

  // freq bin; lanes >= 201 are zero-scale (their contrib is exactly 0 for t>=1)
  const int f = (tid < FF) ? tid : (FF - 1);
  float cs = (tid < FF) ? ((tid == 0 || tid == FF - 1) ? 1.0f : 2.0f) : 0.0f;
  cs *= CSCALE;

  const float2* xb = x + (size_t)b * TT * FF;

  __shared__ float4 part[4][LTILE];

  float s_ring[W1], w_ring[W2];
#pragma unroll
  for (int j = 0; j < W1; ++j) s_ring[j] = 0.f;
#pragma unroll
  for (int j = 0; j < W2; ++j) w_ring[j] = 0.f;
  float ssum = 0.f, wsum = 0.f, lsum = 0.f;

  float2 bufA[10], bufB[10], bufC[10];

  // preload stream groups 0 and 1; pf2 tracks the last-loaded group base
  const float2* p0 = xb + (size_t)tstart * FF + f;
#pragma unroll
  for (int j = 0; j < 10; ++j) bufA[j] = p0[j * FF];
  const float2* pf2 = p0 + 10 * FF;
#pragma unroll
  for (int j = 0; j < 10; ++j) bufB[j] = pf2[j * FF];
  __builtin_amdgcn_sched_barrier(0);

  if (!first) {
    // stream: 1 warm-A + 3 warm-B + 20 main = 24 straight-line groups
    // (frames t0-40..t0+199)
    WARMA_GROUP(0, 24)
    WARMB_GROUP(1, 24)  WARMB_GROUP(2, 24)  WARMB_GROUP(3, 24)
    MAIN_GROUP(4,  24,   0, false)  MAIN_GROUP(5,  24,  10, false)
    MAIN_GROUP(6,  24,  20, false)  MAIN_GROUP(7,  24,  30, false)
    MAIN_GROUP(8,  24,  40, false)  MAIN_GROUP(9,  24,  50, false)
    MAIN_GROUP(10, 24,  60, false)  MAIN_GROUP(11, 24,  70, false)
    MAIN_GROUP(12, 24,  80, false)  MAIN_GROUP(13, 24,  90, false)
    MAIN_GROUP(14, 24, 100, false)  MAIN_GROUP(15, 24, 110, false)
    MAIN_GROUP(16, 24, 120, false)  MAIN_GROUP(17, 24, 130, false)
    MAIN_GROUP(18, 24, 140, false)  MAIN_GROUP(19, 24, 150, false)
    MAIN_GROUP(20, 24, 160, false)  MAIN_GROUP(21, 24, 170, false)
    MAIN_GROUP(22, 24, 180, false)  MAIN_GROUP(23, 24, 190, false)
  } else {
    // tile 0: 20 straight-line main groups (frames 0..199); m<30 DYN
    // (constant-folded), no eviction there.
    MAIN_GROUP(0,  20,   0, true)   MAIN_GROUP(1,  20,  10, true)
    MAIN_GROUP(2,  20,  20, true)   MAIN_GROUP(3,  20,  30, false)
    MAIN_GROUP(4,  20,  40, false)  MAIN_GROUP(5,  20,  50, false)
    MAIN_GROUP(6,  20,  60, false)  MAIN_GROUP(7,  20,  70, false)
    MAIN_GROUP(8,  20,  80, false)  MAIN_GROUP(9,  20,  90, false)
    MAIN_GROUP(10, 20, 100, false)  MAIN_GROUP(11, 20, 110, false)
    MAIN_GROUP(12, 20, 120, false)  MAIN_GROUP(13, 20, 130, false)
    MAIN_GROUP(14, 20, 140, false)  MAIN_GROUP(15, 20, 150, false)
    MAIN_GROUP(16, 20, 160, false)  MAIN_GROUP(17, 20, 170, false)
    MAIN_GROUP(18, 20, 180, false)  MAIN_GROUP(19, 20, 190, false)
  }

  // ---- epilogue: sum the 16 partials (4 waves x 4 lanes) per frame ----
  __syncthreads();
  if (tid < LTILE) {
    float4 v0 = part[0][tid], v1 = part[1][tid];
    float4 v2 = part[2][tid], v3 = part[3][tid];
    float v = ((v0.x + v0.y) + (v0.z + v0.w)) + ((v1.x + v1.y) + (v1.z + v1.w)) +
              ((v2.x + v2.y) + (v2.z + v2.w)) + ((v3.x + v3.y) + (v3.z + v3.w));
    if (first && tid == 0) v = 0.f;  // reference forces frame 0 to exactly 0
    out[(size_t)b * TT + t0 + tid] = v;
  }
}

extern "C" void kernel_launch(void* const* d_in, const int* in_sizes, int n_in,
                              void* d_out, int out_size, void* d_ws, size_t ws_size,
                              hipStream_t stream) {
  const float2* x = (const float2*)d_in[0];
  float* out = (float*)d_out;
  dim3 grid(BB, NT);  // batch fastest: halo source tile lands on same XCD
  ltsf_kernel<<<grid, 256, 0, stream>>>(x, out);
}